// Round 1
// baseline (651.537 us; speedup 1.0000x reference)
//
#include <hip/hip_runtime.h>
#include <math.h>

#define T 512

__global__ __launch_bounds__(512) void gcn_ssa_kernel(
    const float* __restrict__ x,
    const float* __restrict__ wq, const float* __restrict__ bq,
    const float* __restrict__ wk, const float* __restrict__ bk,
    const float* __restrict__ wv, const float* __restrict__ bv,
    const float* __restrict__ gw1, const float* __restrict__ gb1,
    const float* __restrict__ gw2, const float* __restrict__ gb2,
    const float* __restrict__ gammap, const int* __restrict__ idxg,
    float* __restrict__ out)
{
  const int b = blockIdx.x;
  const int tid = threadIdx.x;
  const float* xb = x + (size_t)b * 8192;
  float* outb = out + (size_t)b * 8192;

  // padded stride 129 -> bank(n,h) = (n+h)%32, conflict-free column reads
  __shared__ __align__(16) float fq[64 * 129];
  __shared__ __align__(16) float fk[64 * 129];
  __shared__ __align__(16) float fv[64 * 129];
  __shared__ float adjb[64 * 65];
  __shared__ float t1b[64 * 9];
  __shared__ float hbb[64 * 9];
  __shared__ float rinv_s[64];
  __shared__ float nrm_s[64];
  __shared__ float red0[512];
  __shared__ float red1[512];
  __shared__ float qks[64 * 26];
  __shared__ float Ms[64];
  __shared__ int mtop[25];
  __shared__ int repl[64];

  // ---------- Stage A: load x (temp into fv region), project q,k,v ----------
  {
    float4* xs4 = (float4*)fv;
    const float4* xg4 = (const float4*)xb;
    for (int i = tid; i < 2048; i += T) xs4[i] = xg4[i];
  }
  __syncthreads();
  const float* xs = fv;  // 64x128, linear stride 128 (temp alias)

  float vreg[16];
  {
    int cnt = 0;
    for (int i = tid; i < 8192; i += T, ++cnt) {
      int o = i >> 7, h = i & 127;
      float aq = bq[o], ak = bk[o], av = bv[o];
      const float* wqr = wq + o * 64;
      const float* wkr = wk + o * 64;
      const float* wvr = wv + o * 64;
#pragma unroll 8
      for (int c = 0; c < 64; ++c) {
        float xv = xs[c * 128 + h];
        aq += wqr[c] * xv;
        ak += wkr[c] * xv;
        av += wvr[c] * xv;
      }
      fq[o * 129 + h] = aq;
      fk[o * 129 + h] = ak;
      vreg[cnt] = av;  // fv region still holds x; write later
    }
  }
  __syncthreads();
  {
    int cnt = 0;
    for (int i = tid; i < 8192; i += T, ++cnt) {
      int o = i >> 7, h = i & 127;
      fv[o * 129 + h] = vreg[cnt];
    }
  }
  __syncthreads();

  // ---------- Stage B: branch (row-normalize, adjacency, 2-layer GCN) x3 ----------
  for (int br = 0; br < 3; ++br) {
    float* f = (br == 0) ? fq : (br == 1) ? fk : fv;

    // 1. row stats: sum (for row_normalize) and sum-of-squares (for cosine norm)
    {
      int n = tid >> 3, g = tid & 7;
      float s0 = 0.f, s1 = 0.f;
#pragma unroll
      for (int h = g * 16; h < g * 16 + 16; ++h) {
        float v = f[n * 129 + h];
        s0 += v;
        s1 += v * v;
      }
      red0[tid] = s0;
      red1[tid] = s1;
    }
    __syncthreads();
    if (tid < 64) {
      float su = 0.f, sq = 0.f;
#pragma unroll
      for (int g = 0; g < 8; ++g) {
        su += red0[tid * 8 + g];
        sq += red1[tid * 8 + g];
      }
      rinv_s[tid] = (su == 0.0f) ? 0.0f : (1.0f / su);  // isinf(1/s) -> 0
      nrm_s[tid] = 1.0f / fmaxf(sqrtf(sq), 1e-8f);
    }
    __syncthreads();

    // 2. adjacency: sim>0.5, +I (symmetrization in ref is a no-op: sim symmetric)
    for (int i = tid; i < 4096; i += T) {
      int r = i >> 6, m = i & 63;
      float acc = 0.f;
#pragma unroll 16
      for (int h = 0; h < 128; ++h) acc += f[r * 129 + h] * f[m * 129 + h];
      float sim = acc * nrm_s[r] * nrm_s[m];
      float a = (sim > 0.5f) ? 1.0f : 0.0f;
      if (r == m) a += 1.0f;
      adjb[r * 65 + m] = a;
    }
    __syncthreads();
    // adjacency row sums -> row-normalize in place
    {
      int n = tid >> 3, g = tid & 7;
      float s = 0.f;
#pragma unroll
      for (int m = g * 8; m < g * 8 + 8; ++m) s += adjb[n * 65 + m];
      red0[tid] = s;
    }
    __syncthreads();
    if (tid < 64) {
      float su = 0.f;
#pragma unroll
      for (int g = 0; g < 8; ++g) su += red0[tid * 8 + g];
      nrm_s[tid] = 1.0f / su;  // reuse as adj row inverse (>=1, never 0)
    }
    __syncthreads();
    for (int i = tid; i < 4096; i += T) {
      int r = i >> 6, m = i & 63;
      adjb[r * 65 + m] *= nrm_s[r];
    }
    __syncthreads();

    // 3. t1 = row_normalize(f) @ gw1   (64x8)
    {
      int n = tid >> 3, j = tid & 7;
      float acc = 0.f;
#pragma unroll 16
      for (int h = 0; h < 128; ++h) acc += f[n * 129 + h] * gw1[h * 8 + j];
      t1b[n * 9 + j] = acc * rinv_s[n];
    }
    __syncthreads();
    // 4. h = relu(adjn @ t1 + gb1)
    {
      int n = tid >> 3, j = tid & 7;
      float acc = gb1[j];
#pragma unroll 16
      for (int m = 0; m < 64; ++m) acc += adjb[n * 65 + m] * t1b[m * 9 + j];
      hbb[n * 9 + j] = fmaxf(acc, 0.0f);
    }
    __syncthreads();
    // 5. g = adjn @ h   (assoc: adj@(h@w2) == (adj@h)@w2) -> reuse t1b
    {
      int n = tid >> 3, j = tid & 7;
      float acc = 0.f;
#pragma unroll 16
      for (int m = 0; m < 64; ++m) acc += adjb[n * 65 + m] * hbb[m * 9 + j];
      t1b[n * 9 + j] = acc;
    }
    __syncthreads();
    // 6. f = g @ gw2 + gb2  (in place, f no longer needed)
    for (int i = tid; i < 8192; i += T) {
      int n = i >> 7, h = i & 127;
      float acc = gb2[h];
#pragma unroll
      for (int j = 0; j < 8; ++j) acc += t1b[n * 9 + j] * gw2[j * 128 + h];
      f[n * 129 + h] = acc;
    }
    __syncthreads();
  }

  // ---------- Stage C: ProbSparse attention ----------
  // index_sample into LDS (reuse adjb space: 3200 ints <= 4160 floats)
  int* idxs = (int*)adjb;
  for (int i = tid; i < 3200; i += T) idxs[i] = idxg[i];
  __syncthreads();

  // qk_sample[n][s] = sum_l q[n][l] * k[n][idx[l][s]]
  for (int i = tid; i < 1600; i += T) {
    int n = i / 25, s = i % 25;
    float acc = 0.f;
#pragma unroll 16
    for (int l = 0; l < 128; ++l)
      acc += fq[n * 129 + l] * fk[n * 129 + idxs[l * 25 + s]];
    qks[n * 26 + s] = acc;
  }
  __syncthreads();
  if (tid < 64) {
    float mx = -INFINITY, su = 0.f;
#pragma unroll
    for (int s = 0; s < 25; ++s) {
      float v = qks[tid * 26 + s];
      mx = fmaxf(mx, v);
      su += v;
    }
    Ms[tid] = mx - su * (1.0f / 128.0f);  // Lk = 128
    repl[tid] = 0;
  }
  __syncthreads();

  // top-25 of 64 (value desc, index asc on ties — matches lax.top_k set)
  if (tid < 64) {
    float v = Ms[tid];
    for (int it = 0; it < 25; ++it) {
      float bv2 = v;
      int bi = tid;
#pragma unroll
      for (int off = 32; off > 0; off >>= 1) {
        float ov = __shfl_xor(bv2, off);
        int oi = __shfl_xor(bi, off);
        if (ov > bv2 || (ov == bv2 && oi < bi)) {
          bv2 = ov;
          bi = oi;
        }
      }
      if (tid == 0) mtop[it] = bi;
      if (tid == bi) v = -INFINITY;
    }
  }
  __syncthreads();
  if (tid < 25) repl[mtop[tid]] = 1;
  __syncthreads();

  // dense scores for selected rows (reuse qks as sc[25*64]); scale = 1/sqrt(128)
  float* sc = qks;
  {
    const float scale = 0.08838834764831845f;
    for (int i = tid; i < 1600; i += T) {
      int u = i >> 6, n = i & 63;
      int qrow = mtop[u];
      float acc = 0.f;
#pragma unroll 16
      for (int l = 0; l < 128; ++l) acc += fq[qrow * 129 + l] * fk[n * 129 + l];
      sc[u * 64 + n] = acc * scale;
    }
  }
  __syncthreads();
  // softmax over n (64), one selected row per thread
  if (tid < 25) {
    float mx = -INFINITY;
    for (int n = 0; n < 64; ++n) mx = fmaxf(mx, sc[tid * 64 + n]);
    float su = 0.f;
    for (int n = 0; n < 64; ++n) {
      float e = __expf(sc[tid * 64 + n] - mx);
      sc[tid * 64 + n] = e;
      su += e;
    }
    float inv = 1.0f / su;
    for (int n = 0; n < 64; ++n) sc[tid * 64 + n] *= inv;
  }
  __syncthreads();

  const float gamma = *gammap;
  // updated rows: out[mtop[u]] = gamma * (attn @ values)[u] + x[mtop[u]]
  for (int i = tid; i < 3200; i += T) {
    int u = i >> 7, h = i & 127;
    float acc = 0.f;
#pragma unroll 16
    for (int n = 0; n < 64; ++n) acc += sc[u * 64 + n] * fv[n * 129 + h];
    int row = mtop[u];
    outb[row * 128 + h] = gamma * acc + xb[row * 128 + h];
  }
  // cumsum rows (write only non-replaced rows; accumulate all)
  for (int h = tid; h < 128; h += T) {
    float acc = 0.f;
    for (int n = 0; n < 64; ++n) {
      acc += fv[n * 129 + h];
      if (!repl[n]) outb[n * 128 + h] = gamma * acc + xb[n * 128 + h];
    }
  }
}

extern "C" void kernel_launch(void* const* d_in, const int* in_sizes, int n_in,
                              void* d_out, int out_size, void* d_ws, size_t ws_size,
                              hipStream_t stream) {
  const float* x   = (const float*)d_in[0];
  const float* wq  = (const float*)d_in[1];
  const float* bq  = (const float*)d_in[2];
  const float* wk  = (const float*)d_in[3];
  const float* bk  = (const float*)d_in[4];
  const float* wv  = (const float*)d_in[5];
  const float* bv  = (const float*)d_in[6];
  const float* gw1 = (const float*)d_in[7];
  const float* gb1 = (const float*)d_in[8];
  const float* gw2 = (const float*)d_in[9];
  const float* gb2 = (const float*)d_in[10];
  const float* gm  = (const float*)d_in[11];
  const int* idx   = (const int*)d_in[12];
  float* out = (float*)d_out;
  int B = in_sizes[0] / (64 * 128);
  hipLaunchKernelGGL(gcn_ssa_kernel, dim3(B), dim3(512), 0, stream,
                     x, wq, bq, wk, bk, wv, bv, gw1, gb1, gw2, gb2, gm, idx, out);
}

// Round 2
// 339.774 us; speedup vs baseline: 1.9176x; 1.9176x over previous
//
#include <hip/hip_runtime.h>
#include <math.h>

#define T 1024
#define FS 132   // feature row stride (floats), float4-aligned, bank-delta 4/row
#define FSQ 33   // in float4
#define AS 68    // adj row stride
#define ASQ 17

__device__ __forceinline__ void macc(float& acc, const float4 a, const float4 b) {
  acc = fmaf(a.x, b.x, acc);
  acc = fmaf(a.y, b.y, acc);
  acc = fmaf(a.z, b.z, acc);
  acc = fmaf(a.w, b.w, acc);
}
__device__ __forceinline__ void fma4(float4& a, float s, const float4 b) {
  a.x = fmaf(s, b.x, a.x);
  a.y = fmaf(s, b.y, a.y);
  a.z = fmaf(s, b.z, a.z);
  a.w = fmaf(s, b.w, a.w);
}

__global__ __launch_bounds__(T) void gcn_ssa_kernel(
    const float* __restrict__ x,
    const float* __restrict__ wq, const float* __restrict__ bq,
    const float* __restrict__ wk, const float* __restrict__ bk,
    const float* __restrict__ wv, const float* __restrict__ bv,
    const float* __restrict__ gw1, const float* __restrict__ gb1,
    const float* __restrict__ gw2, const float* __restrict__ gb2,
    const float* __restrict__ gammap, const int* __restrict__ idxg,
    float* __restrict__ out)
{
  const int b = blockIdx.x, tid = threadIdx.x;
  const float* xb = x + (size_t)b * 8192;
  float* outb = out + (size_t)b * 8192;

  __shared__ __align__(16) float fq[64 * FS];
  __shared__ __align__(16) float fk[64 * FS];
  __shared__ __align__(16) float fv[64 * FS];
  __shared__ __align__(16) float U[12480];      // weights | adj/t1T/hT/g/qks/idx
  __shared__ __align__(16) float gw1T[8 * FS];  // gw1 transposed [j][h]
  __shared__ __align__(16) float gw2s[8 * 128];
  __shared__ __align__(16) float gb1s[8];
  __shared__ __align__(16) float gb2s[128];
  __shared__ float rinv_s[64], nrm_s[64], rinv2_s[64], Ms[64];
  __shared__ int mtop[25], repl[64];

  float4* fq4 = (float4*)fq;
  float4* fk4 = (float4*)fk;
  float4* fv4 = (float4*)fv;
  float4* U4 = (float4*)U;

  // ---------------- Stage A0: stage x (into fv, stride FS) + weights ----------------
  {
    const float4* xg = (const float4*)xb;
    for (int i = tid; i < 2048; i += T) {
      int r = i >> 5, cq = i & 31;
      fv4[r * FSQ + cq] = xg[i];
    }
    const float4* wqg = (const float4*)wq;
    const float4* wkg = (const float4*)wk;
    const float4* wvg = (const float4*)wv;
    for (int i = tid; i < 1024; i += T) {
      U4[i] = wqg[i];
      U4[1024 + i] = wkg[i];
      U4[2048 + i] = wvg[i];
    }
    if (tid < 64) {
      U[12288 + tid] = bq[tid];
      U[12352 + tid] = bk[tid];
      U[12416 + tid] = bv[tid];
    }
    for (int i = tid; i < 1024; i += T) {
      int h = i >> 3, j = i & 7;
      gw1T[j * FS + h] = gw1[i];
      gw2s[i] = gw2[i];
    }
    if (tid < 8) gb1s[tid] = gb1[tid];
    if (tid < 128) gb2s[tid] = gb2[tid];
  }
  __syncthreads();

  // ---------------- Stage A1: projection q,k,v (2 o-rows x 4 h per thread) ----------------
  float4 vacc0, vacc1;
  {
    const int o0 = (tid >> 5) << 1;  // wave-half uniform
    const int hq = tid & 31;
    const float4* wqs = U4;                 // [o][cq] stride 16 quads
    const float4* wks = U4 + 1024;
    const float4* wvs = U4 + 2048;
    float4 aq0, aq1, ak0, ak1, av0, av1;
    {
      float bq0 = U[12288 + o0], bq1 = U[12288 + o0 + 1];
      float bk0 = U[12352 + o0], bk1 = U[12352 + o0 + 1];
      float bv0 = U[12416 + o0], bv1 = U[12416 + o0 + 1];
      aq0 = make_float4(bq0, bq0, bq0, bq0); aq1 = make_float4(bq1, bq1, bq1, bq1);
      ak0 = make_float4(bk0, bk0, bk0, bk0); ak1 = make_float4(bk1, bk1, bk1, bk1);
      av0 = make_float4(bv0, bv0, bv0, bv0); av1 = make_float4(bv1, bv1, bv1, bv1);
    }
    for (int cq = 0; cq < 16; ++cq) {
      float4 x0 = fv4[(4 * cq + 0) * FSQ + hq];
      float4 x1 = fv4[(4 * cq + 1) * FSQ + hq];
      float4 x2 = fv4[(4 * cq + 2) * FSQ + hq];
      float4 x3 = fv4[(4 * cq + 3) * FSQ + hq];
      float4 w;
      w = wqs[o0 * 16 + cq];       fma4(aq0, w.x, x0); fma4(aq0, w.y, x1); fma4(aq0, w.z, x2); fma4(aq0, w.w, x3);
      w = wqs[(o0 + 1) * 16 + cq]; fma4(aq1, w.x, x0); fma4(aq1, w.y, x1); fma4(aq1, w.z, x2); fma4(aq1, w.w, x3);
      w = wks[o0 * 16 + cq];       fma4(ak0, w.x, x0); fma4(ak0, w.y, x1); fma4(ak0, w.z, x2); fma4(ak0, w.w, x3);
      w = wks[(o0 + 1) * 16 + cq]; fma4(ak1, w.x, x0); fma4(ak1, w.y, x1); fma4(ak1, w.z, x2); fma4(ak1, w.w, x3);
      w = wvs[o0 * 16 + cq];       fma4(av0, w.x, x0); fma4(av0, w.y, x1); fma4(av0, w.z, x2); fma4(av0, w.w, x3);
      w = wvs[(o0 + 1) * 16 + cq]; fma4(av1, w.x, x0); fma4(av1, w.y, x1); fma4(av1, w.z, x2); fma4(av1, w.w, x3);
    }
    fq4[o0 * FSQ + hq] = aq0;
    fq4[(o0 + 1) * FSQ + hq] = aq1;
    fk4[o0 * FSQ + hq] = ak0;
    fk4[(o0 + 1) * FSQ + hq] = ak1;
    vacc0 = av0; vacc1 = av1;
  }
  __syncthreads();
  {
    const int o0 = (tid >> 5) << 1, hq = tid & 31;
    fv4[o0 * FSQ + hq] = vacc0;
    fv4[(o0 + 1) * FSQ + hq] = vacc1;
  }
  // weights dead -> stage index_sample into U[7616..]
  int* idxs = (int*)(U + 7616);
  for (int i = tid; i < 3200; i += T) idxs[i] = idxg[i];
  __syncthreads();

  float* adjb = U;           // 64*68
  float* t1T = U + 4352;     // 8*68  [j][m]
  float* hT  = U + 4896;     // 8*68  [j][m]
  float* gsm = U + 5440;     // 64*8  [n][j]
  float* qks = U + 5952;     // 64*26
  float4* adj4 = (float4*)adjb;

  // ---------------- Stage B: three GCN branches ----------------
  for (int br = 0; br < 3; ++br) {
    float* f = (br == 0) ? fq : (br == 1) ? fk : fv;
    float4* f4 = (float4*)f;

    // row sum + sumsq (16 lanes per row)
    {
      int row = tid >> 4, g = tid & 15;
      float4 a = f4[row * FSQ + 2 * g];
      float4 c = f4[row * FSQ + 2 * g + 1];
      float s0 = a.x + a.y + a.z + a.w + c.x + c.y + c.z + c.w;
      float s1 = a.x * a.x + a.y * a.y + a.z * a.z + a.w * a.w +
                 c.x * c.x + c.y * c.y + c.z * c.z + c.w * c.w;
      for (int off = 8; off; off >>= 1) {
        s0 += __shfl_xor(s0, off);
        s1 += __shfl_xor(s1, off);
      }
      if (g == 0) {
        rinv_s[row] = (s0 == 0.0f) ? 0.0f : (1.0f / s0);
        nrm_s[row] = 1.0f / fmaxf(sqrtf(s1), 1e-8f);
      }
    }
    __syncthreads();

    // gram -> thresholded adjacency (+I). 4r x 4m register tile, m strided 16.
    if (tid < 256) {
      int rq = tid >> 4, q = tid & 15;
      int r0 = rq * 4;
      float acc[4][4];
#pragma unroll
      for (int i = 0; i < 4; ++i)
#pragma unroll
        for (int j = 0; j < 4; ++j) acc[i][j] = 0.0f;
      for (int hc = 0; hc < 32; ++hc) {
        float4 a0 = f4[(r0 + 0) * FSQ + hc];
        float4 a1 = f4[(r0 + 1) * FSQ + hc];
        float4 a2 = f4[(r0 + 2) * FSQ + hc];
        float4 a3 = f4[(r0 + 3) * FSQ + hc];
        float4 b0 = f4[q * FSQ + hc];
        float4 b1 = f4[(q + 16) * FSQ + hc];
        float4 b2 = f4[(q + 32) * FSQ + hc];
        float4 b3 = f4[(q + 48) * FSQ + hc];
        macc(acc[0][0], a0, b0); macc(acc[0][1], a0, b1); macc(acc[0][2], a0, b2); macc(acc[0][3], a0, b3);
        macc(acc[1][0], a1, b0); macc(acc[1][1], a1, b1); macc(acc[1][2], a1, b2); macc(acc[1][3], a1, b3);
        macc(acc[2][0], a2, b0); macc(acc[2][1], a2, b1); macc(acc[2][2], a2, b2); macc(acc[2][3], a2, b3);
        macc(acc[3][0], a3, b0); macc(acc[3][1], a3, b1); macc(acc[3][2], a3, b2); macc(acc[3][3], a3, b3);
      }
#pragma unroll
      for (int i = 0; i < 4; ++i) {
        int r = r0 + i;
        float nr = nrm_s[r];
#pragma unroll
        for (int j = 0; j < 4; ++j) {
          int m = q + 16 * j;
          float sim = acc[i][j] * nr * nrm_s[m];
          float a = (sim > 0.5f) ? 1.0f : 0.0f;
          if (r == m) a += 1.0f;
          adjb[r * AS + m] = a;
        }
      }
    }
    __syncthreads();

    // adjacency row sums (normalization folded into aggregations)
    {
      int row = tid >> 4, g = tid & 15;
      float4 a = adj4[row * ASQ + g];
      float s = a.x + a.y + a.z + a.w;
      for (int off = 8; off; off >>= 1) s += __shfl_xor(s, off);
      if (g == 0) rinv2_s[row] = 1.0f / s;
    }
    // t1[n][j] = rinv[n] * sum_h f[n][h]*gw1[h][j]  -> t1T[j][n]
    if (tid < 256) {
      int n = tid >> 2, j0 = (tid & 3) * 2;
      float a0 = 0.f, a1 = 0.f;
      const float4* w0 = (const float4*)(gw1T + j0 * FS);
      const float4* w1 = (const float4*)(gw1T + (j0 + 1) * FS);
      for (int hc = 0; hc < 32; ++hc) {
        float4 fx = f4[n * FSQ + hc];
        macc(a0, fx, w0[hc]);
        macc(a1, fx, w1[hc]);
      }
      float rv = rinv_s[n];
      t1T[j0 * AS + n] = a0 * rv;
      t1T[(j0 + 1) * AS + n] = a1 * rv;
    }
    __syncthreads();

    // h = relu(rinv2[n]*(adj@t1) + gb1) -> hT[j][n]
    if (tid < 512) {
      int n = tid >> 3, j = tid & 7;
      float acc = 0.f;
      const float4* a4 = (const float4*)(adjb + n * AS);
      const float4* t4 = (const float4*)(t1T + j * AS);
      for (int mq = 0; mq < 16; ++mq) macc(acc, a4[mq], t4[mq]);
      hT[j * AS + n] = fmaxf(acc * rinv2_s[n] + gb1s[j], 0.0f);
    }
    __syncthreads();

    // g = rinv2[n]*(adj@h) -> gsm[n][j]
    if (tid < 512) {
      int n = tid >> 3, j = tid & 7;
      float acc = 0.f;
      const float4* a4 = (const float4*)(adjb + n * AS);
      const float4* h4 = (const float4*)(hT + j * AS);
      for (int mq = 0; mq < 16; ++mq) macc(acc, a4[mq], h4[mq]);
      gsm[n * 8 + j] = acc * rinv2_s[n];
    }
    __syncthreads();

    // f = g @ gw2 + gb2 (in place; 2 n-rows per thread share weight loads)
    {
      int n0 = tid >> 5, hq = tid & 31;
      int n1 = n0 + 32;
      const float4* g4 = (const float4*)gsm;
      float4 ga0 = g4[n0 * 2], ga1 = g4[n0 * 2 + 1];
      float4 gc0 = g4[n1 * 2], gc1 = g4[n1 * 2 + 1];
      const float* pa0 = (const float*)&ga0;
      const float* pa1 = (const float*)&ga1;
      const float* pc0 = (const float*)&gc0;
      const float* pc1 = (const float*)&gc1;
      const float4* w4 = (const float4*)gw2s;
      float4 bquad = ((const float4*)gb2s)[hq];
      float4 acc0 = bquad, acc1 = bquad;
#pragma unroll
      for (int j = 0; j < 4; ++j) {
        float4 w = w4[j * 32 + hq];
        fma4(acc0, pa0[j], w);
        fma4(acc1, pc0[j], w);
      }
#pragma unroll
      for (int j = 0; j < 4; ++j) {
        float4 w = w4[(j + 4) * 32 + hq];
        fma4(acc0, pa1[j], w);
        fma4(acc1, pc1[j], w);
      }
      f4[n0 * FSQ + hq] = acc0;
      f4[n1 * FSQ + hq] = acc1;
    }
    __syncthreads();
  }

  // ---------------- Stage C: ProbSparse attention ----------------
  // qk_sample[n][s] = sum_l q[n][l]*k[n][idx[l][s]]
  if (tid < 512) {
    int n = tid >> 3, g = tid & 7;
    float a0 = 0.f, a1 = 0.f, a2 = 0.f, a3 = 0.f;
    const float4* q4 = (const float4*)(fq + n * FS);
    const float* kr = fk + n * FS;
    for (int lq = 0; lq < 32; ++lq) {
      float4 qv = q4[lq];
      const float* qp = (const float*)&qv;
#pragma unroll
      for (int ll = 0; ll < 4; ++ll) {
        const int* ip = idxs + (lq * 4 + ll) * 25;
        float qs = qp[ll];
        a0 = fmaf(qs, kr[ip[g]], a0);
        a1 = fmaf(qs, kr[ip[g + 8]], a1);
        a2 = fmaf(qs, kr[ip[g + 16]], a2);
        if (g == 0) a3 = fmaf(qs, kr[ip[24]], a3);
      }
    }
    qks[n * 26 + g] = a0;
    qks[n * 26 + g + 8] = a1;
    qks[n * 26 + g + 16] = a2;
    if (g == 0) qks[n * 26 + 24] = a3;
  }
  __syncthreads();
  if (tid < 64) {
    float mx = -INFINITY, su = 0.f;
#pragma unroll
    for (int s = 0; s < 25; ++s) {
      float v = qks[tid * 26 + s];
      mx = fmaxf(mx, v);
      su += v;
    }
    Ms[tid] = mx - su * (1.0f / 128.0f);
    repl[tid] = 0;
  }
  __syncthreads();
  if (tid < 64) {  // top-25 (value desc, index asc) on wave 0
    float v = Ms[tid];
    for (int it = 0; it < 25; ++it) {
      float bv2 = v;
      int bi = tid;
#pragma unroll
      for (int off = 32; off > 0; off >>= 1) {
        float ov = __shfl_xor(bv2, off);
        int oi = __shfl_xor(bi, off);
        if (ov > bv2 || (ov == bv2 && oi < bi)) { bv2 = ov; bi = oi; }
      }
      if (tid == 0) mtop[it] = bi;
      if (tid == bi) v = -INFINITY;
    }
  }
  __syncthreads();
  if (tid < 25) repl[mtop[tid]] = 1;
  __syncthreads();

  // dense scores for selected rows: sc[u][n], 1u x 4n (n strided 16)
  float* sc = U;  // adj region dead; 25*68 floats
  if (tid < 400) {
    int u = tid >> 4, nq = tid & 15;
    int qrow = mtop[u];
    float a0 = 0.f, a1 = 0.f, a2 = 0.f, a3 = 0.f;
    const float4* q4 = (const float4*)(fq + qrow * FS);
    for (int hc = 0; hc < 32; ++hc) {
      float4 qv = q4[hc];
      macc(a0, qv, fk4[nq * FSQ + hc]);
      macc(a1, qv, fk4[(nq + 16) * FSQ + hc]);
      macc(a2, qv, fk4[(nq + 32) * FSQ + hc]);
      macc(a3, qv, fk4[(nq + 48) * FSQ + hc]);
    }
    const float scale = 0.08838834764831845f;
    sc[u * AS + nq] = a0 * scale;
    sc[u * AS + nq + 16] = a1 * scale;
    sc[u * AS + nq + 32] = a2 * scale;
    sc[u * AS + nq + 48] = a3 * scale;
  }
  __syncthreads();
  // softmax over n (16 lanes per selected row)
  if (tid < 400) {
    int u = tid >> 4, g = tid & 15;
    float4* s4 = (float4*)(sc + u * AS);
    float4 v = s4[g];
    float mx = fmaxf(fmaxf(v.x, v.y), fmaxf(v.z, v.w));
    for (int off = 8; off; off >>= 1) mx = fmaxf(mx, __shfl_xor(mx, off));
    float4 e;
    e.x = __expf(v.x - mx); e.y = __expf(v.y - mx);
    e.z = __expf(v.z - mx); e.w = __expf(v.w - mx);
    float su = e.x + e.y + e.z + e.w;
    for (int off = 8; off; off >>= 1) su += __shfl_xor(su, off);
    float inv = 1.0f / su;
    e.x *= inv; e.y *= inv; e.z *= inv; e.w *= inv;
    s4[g] = e;
  }
  __syncthreads();

  const float gamma = *gammap;
  if (tid < 416) {
    // updated rows: out[mtop[u]] = gamma*(attn@values) + x[mtop[u]]  (2u x 4h)
    int up = tid >> 5, hq = tid & 31;
    int u0 = up * 2, u1 = u0 + 1;
    bool has1 = (u1 < 25);
    int r0 = mtop[u0];
    int r1 = has1 ? mtop[u1] : 0;
    float4 a0 = make_float4(0.f, 0.f, 0.f, 0.f);
    float4 a1 = make_float4(0.f, 0.f, 0.f, 0.f);
    for (int n = 0; n < 64; ++n) {
      float4 vv = fv4[n * FSQ + hq];
      fma4(a0, sc[u0 * AS + n], vv);
      if (has1) fma4(a1, sc[u1 * AS + n], vv);
    }
    const float4* xg = (const float4*)xb;
    float4* og = (float4*)outb;
    float4 xr = xg[r0 * 32 + hq];
    og[r0 * 32 + hq] = make_float4(fmaf(gamma, a0.x, xr.x), fmaf(gamma, a0.y, xr.y),
                                   fmaf(gamma, a0.z, xr.z), fmaf(gamma, a0.w, xr.w));
    if (has1) {
      float4 xr1 = xg[r1 * 32 + hq];
      og[r1 * 32 + hq] = make_float4(fmaf(gamma, a1.x, xr1.x), fmaf(gamma, a1.y, xr1.y),
                                     fmaf(gamma, a1.z, xr1.z), fmaf(gamma, a1.w, xr1.w));
    }
  } else if (tid >= 512 && tid < 640) {
    // cumsum rows (runs concurrently on separate waves)
    int h = tid - 512;
    float acc = 0.f;
    for (int n = 0; n < 64; ++n) {
      acc += fv[n * FS + h];
      if (!repl[n]) outb[n * 128 + h] = fmaf(gamma, acc, xb[n * 128 + h]);
    }
  }
}

extern "C" void kernel_launch(void* const* d_in, const int* in_sizes, int n_in,
                              void* d_out, int out_size, void* d_ws, size_t ws_size,
                              hipStream_t stream) {
  const float* x   = (const float*)d_in[0];
  const float* wq  = (const float*)d_in[1];
  const float* bq  = (const float*)d_in[2];
  const float* wk  = (const float*)d_in[3];
  const float* bk  = (const float*)d_in[4];
  const float* wv  = (const float*)d_in[5];
  const float* bv  = (const float*)d_in[6];
  const float* gw1 = (const float*)d_in[7];
  const float* gb1 = (const float*)d_in[8];
  const float* gw2 = (const float*)d_in[9];
  const float* gb2 = (const float*)d_in[10];
  const float* gm  = (const float*)d_in[11];
  const int* idx   = (const int*)d_in[12];
  float* out = (float*)d_out;
  int B = in_sizes[0] / (64 * 128);
  hipLaunchKernelGGL(gcn_ssa_kernel, dim3(B), dim3(T), 0, stream,
                     x, wq, bq, wk, bk, wv, bv, gw1, gb1, gw2, gb2, gm, idx, out);
}